// Round 8
// baseline (290.218 us; speedup 1.0000x reference)
//
#include <hip/hip_runtime.h>

// MultiHeadSelfAttention: T=1024 B=8 D=1024 H=16 d=64
// cvt(fp32->bf16, 1 dispatch) -> QKV GEMM (128x128, LDS dbuf, 1 barrier/K-step)
// -> V transpose -> flash attention (4 waves x QBLK=16, swapped-QK packed-P,
// fixed-max softmax, XCD-local grid) -> output GEMM (fp32 out)

#define Tn 1024
#define Bn 8
#define Dn 1024
#define Hn 16
#define HDn 64
#define Mn 8192   // T*B
#define Kn 1024   // D

typedef float f32x4 __attribute__((ext_vector_type(4)));
typedef __bf16 bf16x8 __attribute__((ext_vector_type(8)));
typedef unsigned short u16x8 __attribute__((ext_vector_type(8)));
typedef unsigned short u16x4 __attribute__((ext_vector_type(4)));

#define GLL16(g, l)                                                        \
  __builtin_amdgcn_global_load_lds(                                        \
      (const __attribute__((address_space(1))) void*)(g),                  \
      (__attribute__((address_space(3))) void*)(l), 16, 0, 0)

__device__ __forceinline__ unsigned short f2bf(float f) {
  unsigned int u = __float_as_uint(f);
  u += 0x7fffu + ((u >> 16) & 1u);   // round-to-nearest-even
  return (unsigned short)(u >> 16);
}

// compiler-path f32->bf16 (RTE) — fast in hot loops
__device__ __forceinline__ unsigned short bfbits(float f) {
  __bf16 h = (__bf16)f;
  return __builtin_bit_cast(unsigned short, h);
}

// -------- fp32 -> bf16 conversion: x + 4 weights in ONE dispatch -----------
__global__ __launch_bounds__(256) void cvt_all(
    const float* __restrict__ x, const float* __restrict__ s0,
    const float* __restrict__ s1, const float* __restrict__ s2,
    const float* __restrict__ s3, unsigned short* __restrict__ dx,
    unsigned short* __restrict__ d0, unsigned short* __restrict__ d1,
    unsigned short* __restrict__ d2, unsigned short* __restrict__ d3) {
  const int z = blockIdx.z;
  const float* src;
  unsigned short* dst;
  int n4;
  if (z == 0)      { src = x;  dst = dx; n4 = Mn * Kn / 4; }
  else if (z == 1) { src = s0; dst = d0; n4 = Dn * Dn / 4; }
  else if (z == 2) { src = s1; dst = d1; n4 = Dn * Dn / 4; }
  else if (z == 3) { src = s2; dst = d2; n4 = Dn * Dn / 4; }
  else             { src = s3; dst = d3; n4 = Dn * Dn / 4; }
  int i = blockIdx.x * 256 + threadIdx.x;
  const int stride = gridDim.x * 256;
  for (; i < n4; i += stride) {
    const float4 v = ((const float4*)src)[i];
    u16x4 o;
    o.x = f2bf(v.x); o.y = f2bf(v.y); o.z = f2bf(v.z); o.w = f2bf(v.w);
    ((u16x4*)dst)[i] = o;
  }
}

// ---------------- 128x128 bf16 GEMM core (C = A * Bw^T) --------------------
// LDS double-buffered, ONE __syncthreads per K-step (attn-proven pattern):
// stage(next -> buf^1) issued first, then ds_read+MFMA on buf[cur], then the
// barrier (compiler emits vmcnt(0)+lgkmcnt(0) drain) flips buffers.
// No setprio (m190: negative on lockstep 4-wave GEMM), no inline asm.
__device__ __forceinline__ void gemm128_core(
    const unsigned short* __restrict__ A, const unsigned short* __restrict__ Bw,
    unsigned short* lds_a, unsigned short* lds_b,  // each [2][128*32]
    int bm, int bn, f32x4 acc[4][4]) {
  const int tid = threadIdx.x;
  const int lane = tid & 63;
  const int w = tid >> 6;
  const int wr = w >> 1, wc = w & 1;
  const int fr = lane & 15, fg = lane >> 4;

  const int p0 = tid, p1 = tid + 256;
  const int r0 = p0 >> 2, c0 = (p0 & 3) ^ ((r0 ^ (r0 >> 2)) & 3);
  const int r1 = p1 >> 2, c1 = (p1 & 3) ^ ((r1 ^ (r1 >> 2)) & 3);
  const unsigned short* gA0 = A + (size_t)(bm * 128 + r0) * Kn + c0 * 8;
  const unsigned short* gA1 = A + (size_t)(bm * 128 + r1) * Kn + c1 * 8;
  const unsigned short* gB0 = Bw + (size_t)(bn * 128 + r0) * Kn + c0 * 8;
  const unsigned short* gB1 = Bw + (size_t)(bn * 128 + r1) * Kn + c1 * 8;

  int aoff[4], boff[4];
#pragma unroll
  for (int m = 0; m < 4; m++) {
    const int row = wr * 64 + m * 16 + fr;
    aoff[m] = row * 32 + ((fg ^ ((row ^ (row >> 2)) & 3)) * 8);
  }
#pragma unroll
  for (int n = 0; n < 4; n++) {
    const int row = wc * 64 + n * 16 + fr;
    boff[n] = row * 32 + ((fg ^ ((row ^ (row >> 2)) & 3)) * 8);
  }

#define GSTAGE(koff, bi)                                                  \
  do {                                                                    \
    GLL16(gA0 + (koff), &lds_a[(bi) * 4096 + tid * 8]);                   \
    GLL16(gA1 + (koff), &lds_a[(bi) * 4096 + (tid + 256) * 8]);           \
    GLL16(gB0 + (koff), &lds_b[(bi) * 4096 + tid * 8]);                   \
    GLL16(gB1 + (koff), &lds_b[(bi) * 4096 + (tid + 256) * 8]);           \
  } while (0)

  GSTAGE(0, 0);
  __syncthreads();   // buf0 ready (vmcnt drained by barrier)

  for (int kk = 0; kk < 32; ++kk) {
    const int cur = kk & 1;
    if (kk < 31) GSTAGE((kk + 1) * 32, cur ^ 1);  // async into other buffer
    const unsigned short* la = lds_a + cur * 4096;
    const unsigned short* lb = lds_b + cur * 4096;
    bf16x8 af[4], bfr[4];
#pragma unroll
    for (int m = 0; m < 4; m++) af[m] = *(const bf16x8*)&la[aoff[m]];
#pragma unroll
    for (int n = 0; n < 4; n++) bfr[n] = *(const bf16x8*)&lb[boff[n]];
#pragma unroll
    for (int m = 0; m < 4; m++)
#pragma unroll
      for (int n = 0; n < 4; n++)
        acc[m][n] = __builtin_amdgcn_mfma_f32_16x16x32_bf16(af[m], bfr[n],
                                                            acc[m][n], 0, 0, 0);
    __syncthreads();  // reads of cur done + stage of cur^1 landed
  }
#undef GSTAGE
}

// ---------------- QKV projection, scatter to [b,h,t,d] bf16 ----------------
__global__ __launch_bounds__(256) void gemm_qkv(
    const unsigned short* __restrict__ xbf, const unsigned short* __restrict__ wq,
    const unsigned short* __restrict__ wk, const unsigned short* __restrict__ wv,
    const float* __restrict__ bq, const float* __restrict__ bk,
    const float* __restrict__ bv, unsigned short* __restrict__ qd,
    unsigned short* __restrict__ kd, unsigned short* __restrict__ vd) {
  __shared__ __align__(16) unsigned short lds_a[2 * 128 * 32];
  __shared__ __align__(16) unsigned short lds_b[2 * 128 * 32];
  const int z = blockIdx.z;
  const unsigned short* Bw = (z == 0) ? wq : (z == 1) ? wk : wv;
  const float* bias = (z == 0) ? bq : (z == 1) ? bk : bv;
  unsigned short* dst = (z == 0) ? qd : (z == 1) ? kd : vd;
  // fold 1/sqrt(64) AND log2(e) into Q so softmax can use exp2 directly
  const float sc = (z == 0) ? 0.125f * 1.44269504088896f : 1.0f;

  f32x4 acc[4][4] = {};
  gemm128_core(xbf, Bw, lds_a, lds_b, blockIdx.x, blockIdx.y, acc);

  const int tid = threadIdx.x, lane = tid & 63, w = tid >> 6;
  const int wr = w >> 1, wc = w & 1, fr = lane & 15, fg = lane >> 4;
#pragma unroll
  for (int n = 0; n < 4; n++) {
    const int gcol = blockIdx.y * 128 + wc * 64 + n * 16 + fr;
    const float bc = bias[gcol];
    const int hh = gcol >> 6, dd = gcol & 63;
#pragma unroll
    for (int m = 0; m < 4; m++) {
      const int rowbase = blockIdx.x * 128 + wr * 64 + m * 16 + fg * 4;
#pragma unroll
      for (int r = 0; r < 4; r++) {
        const int grow = rowbase + r;       // m-row = t*B + b
        const int tt = grow >> 3, bb = grow & 7;
        const float v = (acc[m][n][r] + bc) * sc;
        dst[((size_t)(bb * Hn + hh) * Tn + tt) * HDn + dd] = f2bf(v);
      }
    }
  }
}

// ---------------- output projection: fp32 out = A @ Wo^T + bo --------------
__global__ __launch_bounds__(256) void gemm_out(
    const unsigned short* __restrict__ abf, const unsigned short* __restrict__ wo,
    const float* __restrict__ bo, float* __restrict__ out) {
  __shared__ __align__(16) unsigned short lds_a[2 * 128 * 32];
  __shared__ __align__(16) unsigned short lds_b[2 * 128 * 32];
  f32x4 acc[4][4] = {};
  gemm128_core(abf, wo, lds_a, lds_b, blockIdx.x, blockIdx.y, acc);

  const int tid = threadIdx.x, lane = tid & 63, w = tid >> 6;
  const int wr = w >> 1, wc = w & 1, fr = lane & 15, fg = lane >> 4;
#pragma unroll
  for (int n = 0; n < 4; n++) {
    const int gcol = blockIdx.y * 128 + wc * 64 + n * 16 + fr;
    const float bc = bo[gcol];
#pragma unroll
    for (int m = 0; m < 4; m++) {
      const int rowbase = blockIdx.x * 128 + wr * 64 + m * 16 + fg * 4;
#pragma unroll
      for (int r = 0; r < 4; r++) {
        const int grow = rowbase + r;
        out[(size_t)grow * Dn + gcol] = acc[m][n][r] + bc;
      }
    }
  }
}

// ---------------- V transpose: [bh][t][64] -> [bh][64][t] ------------------
__global__ __launch_bounds__(256) void transpose_v(
    const unsigned short* __restrict__ src, unsigned short* __restrict__ dst) {
  __shared__ unsigned short tile[64][72];
  const int tid = threadIdx.x;
  const size_t base = (size_t)blockIdx.y * ((size_t)Tn * HDn);
  const int t0 = blockIdx.x * 64;
#pragma unroll
  for (int it = 0; it < 2; it++) {
    const int p = it * 256 + tid;
    const int r = p >> 3, c = (p & 7) * 8;
    *(u16x8*)&tile[r][c] =
        *(const u16x8*)(src + base + (size_t)(t0 + r) * HDn + c);
  }
  __syncthreads();
#pragma unroll
  for (int it = 0; it < 2; it++) {
    const int p = it * 256 + tid;
    const int d = p >> 3, tc = (p & 7) * 8;
    u16x8 v;
#pragma unroll
    for (int j = 0; j < 8; j++) v[j] = tile[tc + j][d];
    *(u16x8*)(dst + base + (size_t)d * Tn + t0 + tc) = v;
  }
}

// ------ flash attention: 4 waves x QBLK=16, swapped-QK, packed P -----------
// grid (B*H, T/64): all 16 q-tile blocks of one (b,h) share XCD bh%8 -> K/V
// L2-resident. Wave w owns q-rows [w*16, w*16+16).
// S^T = mfma(K,Q): lane's 4 C/D values = 4 CONSECUTIVE keys of q-row fr ->
// P written as 4 packed b64 per tile. Fixed max FM=12 (exp2 domain).
// Row-sum via MFMA(P, ones). O: row=q (fg*4+r), col=d (fr).
__global__ __launch_bounds__(256) void attn_fwd(
    const unsigned short* __restrict__ Q, const unsigned short* __restrict__ K,
    const unsigned short* __restrict__ Vt, unsigned short* __restrict__ Ob) {
  __shared__ __align__(16) unsigned short k2[2][64 * 64];
  __shared__ __align__(16) unsigned short v2[2][64 * 64];
  __shared__ __align__(16) unsigned short p_all[64 * 64];  // Q stage, then P

  const int tid = threadIdx.x, lane = tid & 63, w = tid >> 6;
  const int fr = lane & 15, fg = lane >> 4;
  const int bh = blockIdx.x;          // b*H + h  (XCD = bh%8 locality)
  const int qt = blockIdx.y;          // 64-row q tile
  const int bb = bh >> 4, hh = bh & 15;

  const unsigned short* Qbh = Q + (size_t)bh * (Tn * HDn);
  const unsigned short* Kbh = K + (size_t)bh * (Tn * HDn);
  const unsigned short* Vbh = Vt + (size_t)bh * (HDn * Tn);

  const int p0 = tid, p1 = tid + 256;
  const int r0 = p0 >> 3, c0 = (p0 & 7) ^ (r0 & 7);
  const int r1 = p1 >> 3, c1 = (p1 & 7) ^ (r1 & 7);

  // stage Q tile into p_all; fragments to registers
  GLL16(Qbh + (size_t)(qt * 64 + r0) * HDn + c0 * 8, &p_all[p0 * 8]);
  GLL16(Qbh + (size_t)(qt * 64 + r1) * HDn + c1 * 8, &p_all[p1 * 8]);
  __syncthreads();
  bf16x8 qa[2];
#pragma unroll
  for (int ks = 0; ks < 2; ks++) {
    const int row = w * 16 + fr;
    const int blk = (ks * 4 + fg) ^ (row & 7);
    qa[ks] = *(const bf16x8*)&p_all[row * 64 + blk * 8];
  }

  bf16x8 vones;
#pragma unroll
  for (int j = 0; j < 8; j++) vones[j] = (__bf16)1.0f;

#define STAGE_KV(nx, bi)                                                     \
  do {                                                                       \
    GLL16(Kbh + (size_t)((nx) * 64 + r0) * HDn + c0 * 8, &k2[bi][p0 * 8]);   \
    GLL16(Kbh + (size_t)((nx) * 64 + r1) * HDn + c1 * 8, &k2[bi][p1 * 8]);   \
    GLL16(Vbh + (size_t)r0 * Tn + (nx) * 64 + c0 * 8, &v2[bi][p0 * 8]);      \
    GLL16(Vbh + (size_t)r1 * Tn + (nx) * 64 + c1 * 8, &v2[bi][p1 * 8]);      \
  } while (0)

  STAGE_KV(0, 0);
  __syncthreads();   // drains vmcnt (tile 0) and lgkmcnt (qa reads)

  f32x4 o[4] = {};
  float lsum[4] = {};
  const float FM = 12.0f;                        // fixed max, exp2 domain

  for (int kt = 0; kt < 16; kt++) {
    const int cur = kt & 1;
    if (kt < 15) STAGE_KV(kt + 1, cur ^ 1);      // async into other buffer
    const unsigned short* kl = k2[cur];
    const unsigned short* vl = v2[cur];

    // S^T = K * Q^T : lane holds q-row w*16+fr, keys n*16 + fg*4 + r
    f32x4 s[4] = {};
    __builtin_amdgcn_s_setprio(1);
#pragma unroll
    for (int n = 0; n < 4; n++)
#pragma unroll
      for (int ks = 0; ks < 2; ks++) {
        const int krow = n * 16 + fr;
        const int blk = (ks * 4 + fg) ^ (krow & 7);
        const bf16x8 kb = *(const bf16x8*)&kl[krow * 64 + blk * 8];
        s[n] = __builtin_amdgcn_mfma_f32_16x16x32_bf16(kb, qa[ks], s[n], 0, 0, 0);
      }
    __builtin_amdgcn_s_setprio(0);

    // P = exp2(S - FM): packed b64 writes. Keys n*16+fg*4+{0..3} live in
    // logical 16B-block 2n+(fg>>1), half (fg&1)*4; phys block ^= (fr&7).
#pragma unroll
    for (int n = 0; n < 4; n++) {
      u16x4 pk;
#pragma unroll
      for (int r = 0; r < 4; r++) pk[r] = bfbits(exp2f(s[n][r] - FM));
      const int addr = (w * 16 + fr) * 64 +
                       (((2 * n + (fg >> 1)) ^ (fr & 7)) * 8) + (fg & 1) * 4;
      *(u16x4*)&p_all[addr] = pk;
    }

    // A-fragments of P (row=q-row fr, k=keys ks*32+fg*8..+7)
    bf16x8 pa[2];
#pragma unroll
    for (int ks = 0; ks < 2; ks++) {
      const int blk = (ks * 4 + fg) ^ (fr & 7);
      pa[ks] = *(const bf16x8*)&p_all[(w * 16 + fr) * 64 + blk * 8];
    }

    // row-sum via MFMA(P, ones): C/D row = fg*4+r = q-row slot
    f32x4 ss = {};
    ss = __builtin_amdgcn_mfma_f32_16x16x32_bf16(pa[0], vones, ss, 0, 0, 0);
    ss = __builtin_amdgcn_mfma_f32_16x16x32_bf16(pa[1], vones, ss, 0, 0, 0);
#pragma unroll
    for (int r = 0; r < 4; r++) lsum[r] += ss[r];

    // O += P * V  (B-operand from V^T tile)
    __builtin_amdgcn_s_setprio(1);
#pragma unroll
    for (int ks = 0; ks < 2; ks++)
#pragma unroll
      for (int n = 0; n < 4; n++) {
        const int vrow = n * 16 + fr;
        const int vblk = (ks * 4 + fg) ^ (vrow & 7);
        const bf16x8 vb = *(const bf16x8*)&vl[vrow * 64 + vblk * 8];
        o[n] = __builtin_amdgcn_mfma_f32_16x16x32_bf16(pa[ks], vb, o[n], 0, 0, 0);
      }
    __builtin_amdgcn_s_setprio(0);
    __syncthreads();   // reads of cur done + stage of cur^1 landed
  }
#undef STAGE_KV

  // epilogue: normalize, scatter to attn buffer [t*B+b][D] bf16
#pragma unroll
  for (int r = 0; r < 4; r++) lsum[r] = 1.0f / lsum[r];
  const int tbase = qt * 64 + w * 16 + fg * 4;
#pragma unroll
  for (int n = 0; n < 4; n++) {
    const int dcol = n * 16 + fr;
#pragma unroll
    for (int r = 0; r < 4; r++) {
      const int tt = tbase + r;
      const float val = o[n][r] * lsum[r];
      Ob[((size_t)(tt * Bn + bb)) * Dn + hh * HDn + dcol] = bfbits(val);
    }
  }
}

// ---------------- launch ---------------------------------------------------
extern "C" void kernel_launch(void* const* d_in, const int* in_sizes, int n_in,
                              void* d_out, int out_size, void* d_ws,
                              size_t ws_size, hipStream_t stream) {
  (void)in_sizes; (void)n_in; (void)out_size; (void)ws_size;
  const float* x  = (const float*)d_in[0];
  const float* Wq = (const float*)d_in[1];
  const float* bq = (const float*)d_in[2];
  const float* Wk = (const float*)d_in[3];
  const float* bk = (const float*)d_in[4];
  const float* Wv = (const float*)d_in[5];
  const float* bv = (const float*)d_in[6];
  const float* Wo = (const float*)d_in[7];
  const float* bo = (const float*)d_in[8];
  float* out = (float*)d_out;

  // workspace carve-up (u16 elements), high-water 72 MB (proven size).
  // Aliases (stream-ordered, safe):
  //   vtb = xbf  (xbf dead after gemm_qkv; vtb written by transpose_v after)
  //   ab  = vb   (vb dead after transpose_v; ab written by attn_fwd after)
  unsigned short* ws  = (unsigned short*)d_ws;
  unsigned short* xbf = ws;                               // [8192][1024] 16MB
  unsigned short* wqb = xbf + (size_t)Mn * Kn;            // [1024][1024] 2MB
  unsigned short* wkb = wqb + (size_t)Dn * Dn;
  unsigned short* wvb = wkb + (size_t)Dn * Dn;
  unsigned short* wob = wvb + (size_t)Dn * Dn;
  unsigned short* qb  = wob + (size_t)Dn * Dn;            // [b][h][t][d] 16MB
  unsigned short* kb  = qb + (size_t)Mn * Dn;             // 16MB
  unsigned short* vb  = kb + (size_t)Mn * Dn;             // 16MB
  unsigned short* vtb = xbf;                              // [b][h][d][t] alias
  unsigned short* ab  = vb;                               // [t*B+b][D] alias

  cvt_all<<<dim3(512, 1, 5), 256, 0, stream>>>(
      x, Wq, Wk, Wv, Wo, xbf, wqb, wkb, wvb, wob);

  gemm_qkv<<<dim3(Mn / 128, Dn / 128, 3), 256, 0, stream>>>(
      xbf, wqb, wkb, wvb, bq, bk, bv, qb, kb, vb);
  transpose_v<<<dim3(Tn / 64, Bn * Hn), 256, 0, stream>>>(vb, vtb);
  attn_fwd<<<dim3(Bn * Hn, Tn / 64), 256, 0, stream>>>(qb, kb, vtb, ab);
  gemm_out<<<dim3(Mn / 128, Dn / 128), 256, 0, stream>>>(ab, wob, bo, out);
}

// Round 10
// 268.057 us; speedup vs baseline: 1.0827x; 1.0827x over previous
//
#include <hip/hip_runtime.h>

// MultiHeadSelfAttention: T=1024 B=8 D=1024 H=16 d=64
// cvt(fp32->bf16, 1 flat dispatch) -> QKV GEMM (128x128 tile, BK=64,
// single-buffered LDS, 2 barriers/K-tile) -> V transpose -> flash attention
// (4 waves x QBLK=16, swapped-QK packed-P, fixed-max softmax, XCD-local grid)
// -> output GEMM (fp32 out)

#define Tn 1024
#define Bn 8
#define Dn 1024
#define Hn 16
#define HDn 64
#define Mn 8192   // T*B
#define Kn 1024   // D

typedef float f32x4 __attribute__((ext_vector_type(4)));
typedef __bf16 bf16x8 __attribute__((ext_vector_type(8)));
typedef unsigned short u16x8 __attribute__((ext_vector_type(8)));
typedef unsigned short u16x4 __attribute__((ext_vector_type(4)));

#define GLL16(g, l)                                                        \
  __builtin_amdgcn_global_load_lds(                                        \
      (const __attribute__((address_space(1))) void*)(g),                  \
      (__attribute__((address_space(3))) void*)(l), 16, 0, 0)

__device__ __forceinline__ unsigned short f2bf(float f) {
  unsigned int u = __float_as_uint(f);
  u += 0x7fffu + ((u >> 16) & 1u);   // round-to-nearest-even
  return (unsigned short)(u >> 16);
}

// compiler-path f32->bf16 (RTE) — fast in hot loops
__device__ __forceinline__ unsigned short bfbits(float f) {
  __bf16 h = (__bf16)f;
  return __builtin_bit_cast(unsigned short, h);
}

// -------- fp32 -> bf16: x + 4 weights in ONE flat balanced dispatch --------
__global__ __launch_bounds__(256) void cvt_all(
    const float* __restrict__ x, const float* __restrict__ w0,
    const float* __restrict__ w1, const float* __restrict__ w2,
    const float* __restrict__ w3, unsigned short* __restrict__ dx,
    unsigned short* __restrict__ d0, unsigned short* __restrict__ d1,
    unsigned short* __restrict__ d2, unsigned short* __restrict__ d3) {
  const int NX = Mn * Kn / 4;            // 2,097,152 float4 groups (x)
  const int NW = Dn * Dn / 4;            // 262,144 per weight
  const int NT = NX + 4 * NW;
  int i = blockIdx.x * 256 + threadIdx.x;
  const int stride = gridDim.x * 256;
  for (; i < NT; i += stride) {
    const float* src;
    unsigned short* dst;
    int j;
    if (i < NX) {
      src = x; dst = dx; j = i;
    } else {
      const int t = i - NX;
      const int wsel = t >> 18;          // NW = 2^18
      j = t & (NW - 1);
      src = (wsel == 0) ? w0 : (wsel == 1) ? w1 : (wsel == 2) ? w2 : w3;
      dst = (wsel == 0) ? d0 : (wsel == 1) ? d1 : (wsel == 2) ? d2 : d3;
    }
    const float4 v = ((const float4*)src)[j];
    u16x4 o;
    o.x = f2bf(v.x); o.y = f2bf(v.y); o.z = f2bf(v.z); o.w = f2bf(v.w);
    ((u16x4*)dst)[j] = o;
  }
}

// ---------------- 128x128 bf16 GEMM core, BK=64 (C = A * Bw^T) -------------
// Single-buffered LDS tiles [128][64] (16KB each, 32KB total), rows = 128B.
// Swizzle: 16B-block b of row r lives at phys block b ^ (r&7) (attn-proven:
// 16 fr-lanes spread 2/bank = free). 2 barriers per K-tile of 64 -> half the
// drain events per MFMA vs BK=32. No dbuf (m99/m100/R8: null-to-negative),
// no setprio (m190: negative on lockstep GEMM).
__device__ __forceinline__ void gemm128_core(
    const unsigned short* __restrict__ A, const unsigned short* __restrict__ Bw,
    unsigned short* lds_a, unsigned short* lds_b,  // each [128*64]
    int bm, int bn, f32x4 acc[4][4]) {
  const int tid = threadIdx.x;
  const int lane = tid & 63;
  const int w = tid >> 6;
  const int wr = w >> 1, wc = w & 1;
  const int fr = lane & 15, fg = lane >> 4;

  // staging: 4 chunks of 16B per thread per matrix; LDS dest is linear p*16B,
  // global source pre-swizzled so swizzled reads see logical data.
  int goffA[4], goffB[4];
#pragma unroll
  for (int i = 0; i < 4; i++) {
    const int p = tid + 256 * i;
    const int r = p >> 3, cblk = (p & 7) ^ (r & 7);
    goffA[i] = (bm * 128 + r) * Kn + cblk * 8;
    goffB[i] = (bn * 128 + r) * Kn + cblk * 8;
  }
  // fragment read offsets (elements), per m/n and per kk
  int aoff[4][2], boff[4][2];
#pragma unroll
  for (int m = 0; m < 4; m++) {
    const int row = wr * 64 + m * 16 + fr;
#pragma unroll
    for (int kk = 0; kk < 2; kk++)
      aoff[m][kk] = row * 64 + (((kk * 4 + fg) ^ (row & 7)) * 8);
  }
#pragma unroll
  for (int n = 0; n < 4; n++) {
    const int row = wc * 64 + n * 16 + fr;
#pragma unroll
    for (int kk = 0; kk < 2; kk++)
      boff[n][kk] = row * 64 + (((kk * 4 + fg) ^ (row & 7)) * 8);
  }

  for (int kt = 0; kt < 16; ++kt) {
    const int kbase = kt * 64;
#pragma unroll
    for (int i = 0; i < 4; i++) {
      GLL16(A + goffA[i] + kbase, &lds_a[(tid + 256 * i) * 8]);
      GLL16(Bw + goffB[i] + kbase, &lds_b[(tid + 256 * i) * 8]);
    }
    __syncthreads();   // barrier drains vmcnt: tile ready
#pragma unroll
    for (int kk = 0; kk < 2; kk++) {
      bf16x8 af[4], bfr[4];
#pragma unroll
      for (int m = 0; m < 4; m++) af[m] = *(const bf16x8*)&lds_a[aoff[m][kk]];
#pragma unroll
      for (int n = 0; n < 4; n++) bfr[n] = *(const bf16x8*)&lds_b[boff[n][kk]];
#pragma unroll
      for (int m = 0; m < 4; m++)
#pragma unroll
        for (int n = 0; n < 4; n++)
          acc[m][n] = __builtin_amdgcn_mfma_f32_16x16x32_bf16(
              af[m], bfr[n], acc[m][n], 0, 0, 0);
    }
    __syncthreads();   // compute done before next stage overwrites
  }
}

// ---------------- QKV projection, scatter to [b,h,t,d] bf16 ----------------
__global__ __launch_bounds__(256) void gemm_qkv(
    const unsigned short* __restrict__ xbf, const unsigned short* __restrict__ wq,
    const unsigned short* __restrict__ wk, const unsigned short* __restrict__ wv,
    const float* __restrict__ bq, const float* __restrict__ bk,
    const float* __restrict__ bv, unsigned short* __restrict__ qd,
    unsigned short* __restrict__ kd, unsigned short* __restrict__ vd) {
  __shared__ __align__(16) unsigned short lds_a[128 * 64];
  __shared__ __align__(16) unsigned short lds_b[128 * 64];
  const int z = blockIdx.z;
  const unsigned short* Bw = (z == 0) ? wq : (z == 1) ? wk : wv;
  const float* bias = (z == 0) ? bq : (z == 1) ? bk : bv;
  unsigned short* dst = (z == 0) ? qd : (z == 1) ? kd : vd;
  // fold 1/sqrt(64) AND log2(e) into Q so softmax can use exp2 directly
  const float sc = (z == 0) ? 0.125f * 1.44269504088896f : 1.0f;

  f32x4 acc[4][4] = {};
  gemm128_core(xbf, Bw, lds_a, lds_b, blockIdx.x, blockIdx.y, acc);

  const int tid = threadIdx.x, lane = tid & 63, w = tid >> 6;
  const int wr = w >> 1, wc = w & 1, fr = lane & 15, fg = lane >> 4;
#pragma unroll
  for (int n = 0; n < 4; n++) {
    const int gcol = blockIdx.y * 128 + wc * 64 + n * 16 + fr;
    const float bc = bias[gcol];
    const int hh = gcol >> 6, dd = gcol & 63;
#pragma unroll
    for (int m = 0; m < 4; m++) {
      const int rowbase = blockIdx.x * 128 + wr * 64 + m * 16 + fg * 4;
#pragma unroll
      for (int r = 0; r < 4; r++) {
        const int grow = rowbase + r;       // m-row = t*B + b
        const int tt = grow >> 3, bb = grow & 7;
        const float v = (acc[m][n][r] + bc) * sc;
        dst[((size_t)(bb * Hn + hh) * Tn + tt) * HDn + dd] = f2bf(v);
      }
    }
  }
}

// ---------------- output projection: fp32 out = A @ Wo^T + bo --------------
__global__ __launch_bounds__(256) void gemm_out(
    const unsigned short* __restrict__ abf, const unsigned short* __restrict__ wo,
    const float* __restrict__ bo, float* __restrict__ out) {
  __shared__ __align__(16) unsigned short lds_a[128 * 64];
  __shared__ __align__(16) unsigned short lds_b[128 * 64];
  f32x4 acc[4][4] = {};
  gemm128_core(abf, wo, lds_a, lds_b, blockIdx.x, blockIdx.y, acc);

  const int tid = threadIdx.x, lane = tid & 63, w = tid >> 6;
  const int wr = w >> 1, wc = w & 1, fr = lane & 15, fg = lane >> 4;
#pragma unroll
  for (int n = 0; n < 4; n++) {
    const int gcol = blockIdx.y * 128 + wc * 64 + n * 16 + fr;
    const float bc = bo[gcol];
#pragma unroll
    for (int m = 0; m < 4; m++) {
      const int rowbase = blockIdx.x * 128 + wr * 64 + m * 16 + fg * 4;
#pragma unroll
      for (int r = 0; r < 4; r++) {
        const int grow = rowbase + r;
        out[(size_t)grow * Dn + gcol] = acc[m][n][r] + bc;
      }
    }
  }
}

// ---------------- V transpose: [bh][t][64] -> [bh][64][t] ------------------
__global__ __launch_bounds__(256) void transpose_v(
    const unsigned short* __restrict__ src, unsigned short* __restrict__ dst) {
  __shared__ unsigned short tile[64][72];
  const int tid = threadIdx.x;
  const size_t base = (size_t)blockIdx.y * ((size_t)Tn * HDn);
  const int t0 = blockIdx.x * 64;
#pragma unroll
  for (int it = 0; it < 2; it++) {
    const int p = it * 256 + tid;
    const int r = p >> 3, c = (p & 7) * 8;
    *(u16x8*)&tile[r][c] =
        *(const u16x8*)(src + base + (size_t)(t0 + r) * HDn + c);
  }
  __syncthreads();
#pragma unroll
  for (int it = 0; it < 2; it++) {
    const int p = it * 256 + tid;
    const int d = p >> 3, tc = (p & 7) * 8;
    u16x8 v;
#pragma unroll
    for (int j = 0; j < 8; j++) v[j] = tile[tc + j][d];
    *(u16x8*)(dst + base + (size_t)d * Tn + t0 + tc) = v;
  }
}

// ------ flash attention: 4 waves x QBLK=16, swapped-QK, packed P -----------
// (R7-exact, proven 77.6 us.) grid (B*H, T/64): all 16 q-tile blocks of one
// (b,h) share XCD bh%8 -> K/V L2-resident. Wave w owns q-rows [w*16, w*16+16).
// S^T = mfma(K,Q): lane's 4 C/D values = 4 CONSECUTIVE keys of q-row fr ->
// P written as 4 packed b64 per tile. Fixed max FM=12 (exp2 domain).
// Row-sum via MFMA(P, ones). O: row=q (fg*4+r), col=d (fr).
__global__ __launch_bounds__(256) void attn_fwd(
    const unsigned short* __restrict__ Q, const unsigned short* __restrict__ K,
    const unsigned short* __restrict__ Vt, unsigned short* __restrict__ Ob) {
  __shared__ __align__(16) unsigned short k2[2][64 * 64];
  __shared__ __align__(16) unsigned short v2[2][64 * 64];
  __shared__ __align__(16) unsigned short p_all[64 * 64];  // Q stage, then P

  const int tid = threadIdx.x, lane = tid & 63, w = tid >> 6;
  const int fr = lane & 15, fg = lane >> 4;
  const int bh = blockIdx.x;          // b*H + h  (XCD = bh%8 locality)
  const int qt = blockIdx.y;          // 64-row q tile
  const int bb = bh >> 4, hh = bh & 15;

  const unsigned short* Qbh = Q + (size_t)bh * (Tn * HDn);
  const unsigned short* Kbh = K + (size_t)bh * (Tn * HDn);
  const unsigned short* Vbh = Vt + (size_t)bh * (HDn * Tn);

  const int p0 = tid, p1 = tid + 256;
  const int r0 = p0 >> 3, c0 = (p0 & 7) ^ (r0 & 7);
  const int r1 = p1 >> 3, c1 = (p1 & 7) ^ (r1 & 7);

  // stage Q tile into p_all; fragments to registers
  GLL16(Qbh + (size_t)(qt * 64 + r0) * HDn + c0 * 8, &p_all[p0 * 8]);
  GLL16(Qbh + (size_t)(qt * 64 + r1) * HDn + c1 * 8, &p_all[p1 * 8]);
  __syncthreads();
  bf16x8 qa[2];
#pragma unroll
  for (int ks = 0; ks < 2; ks++) {
    const int row = w * 16 + fr;
    const int blk = (ks * 4 + fg) ^ (row & 7);
    qa[ks] = *(const bf16x8*)&p_all[row * 64 + blk * 8];
  }

  bf16x8 vones;
#pragma unroll
  for (int j = 0; j < 8; j++) vones[j] = (__bf16)1.0f;

#define STAGE_KV(nx, bi)                                                     \
  do {                                                                       \
    GLL16(Kbh + (size_t)((nx) * 64 + r0) * HDn + c0 * 8, &k2[bi][p0 * 8]);   \
    GLL16(Kbh + (size_t)((nx) * 64 + r1) * HDn + c1 * 8, &k2[bi][p1 * 8]);   \
    GLL16(Vbh + (size_t)r0 * Tn + (nx) * 64 + c0 * 8, &v2[bi][p0 * 8]);      \
    GLL16(Vbh + (size_t)r1 * Tn + (nx) * 64 + c1 * 8, &v2[bi][p1 * 8]);      \
  } while (0)

  STAGE_KV(0, 0);
  __syncthreads();   // drains vmcnt (tile 0) and lgkmcnt (qa reads)

  f32x4 o[4] = {};
  float lsum[4] = {};
  const float FM = 12.0f;                        // fixed max, exp2 domain

  for (int kt = 0; kt < 16; kt++) {
    const int cur = kt & 1;
    if (kt < 15) STAGE_KV(kt + 1, cur ^ 1);      // async into other buffer
    const unsigned short* kl = k2[cur];
    const unsigned short* vl = v2[cur];

    // S^T = K * Q^T : lane holds q-row w*16+fr, keys n*16 + fg*4 + r
    f32x4 s[4] = {};
    __builtin_amdgcn_s_setprio(1);
#pragma unroll
    for (int n = 0; n < 4; n++)
#pragma unroll
      for (int ks = 0; ks < 2; ks++) {
        const int krow = n * 16 + fr;
        const int blk = (ks * 4 + fg) ^ (krow & 7);
        const bf16x8 kb = *(const bf16x8*)&kl[krow * 64 + blk * 8];
        s[n] = __builtin_amdgcn_mfma_f32_16x16x32_bf16(kb, qa[ks], s[n], 0, 0, 0);
      }
    __builtin_amdgcn_s_setprio(0);

    // P = exp2(S - FM): packed b64 writes. Keys n*16+fg*4+{0..3} live in
    // logical 16B-block 2n+(fg>>1), half (fg&1)*4; phys block ^= (fr&7).
#pragma unroll
    for (int n = 0; n < 4; n++) {
      u16x4 pk;
#pragma unroll
      for (int r = 0; r < 4; r++) pk[r] = bfbits(exp2f(s[n][r] - FM));
      const int addr = (w * 16 + fr) * 64 +
                       (((2 * n + (fg >> 1)) ^ (fr & 7)) * 8) + (fg & 1) * 4;
      *(u16x4*)&p_all[addr] = pk;
    }

    // A-fragments of P (row=q-row fr, k=keys ks*32+fg*8..+7)
    bf16x8 pa[2];
#pragma unroll
    for (int ks = 0; ks < 2; ks++) {
      const int blk = (ks * 4 + fg) ^ (fr & 7);
      pa[ks] = *(const bf16x8*)&p_all[(w * 16 + fr) * 64 + blk * 8];
    }

    // row-sum via MFMA(P, ones): C/D row = fg*4+r = q-row slot
    f32x4 ss = {};
    ss = __builtin_amdgcn_mfma_f32_16x16x32_bf16(pa[0], vones, ss, 0, 0, 0);
    ss = __builtin_amdgcn_mfma_f32_16x16x32_bf16(pa[1], vones, ss, 0, 0, 0);
#pragma unroll
    for (int r = 0; r < 4; r++) lsum[r] += ss[r];

    // O += P * V  (B-operand from V^T tile)
    __builtin_amdgcn_s_setprio(1);
#pragma unroll
    for (int ks = 0; ks < 2; ks++)
#pragma unroll
      for (int n = 0; n < 4; n++) {
        const int vrow = n * 16 + fr;
        const int vblk = (ks * 4 + fg) ^ (vrow & 7);
        const bf16x8 vb = *(const bf16x8*)&vl[vrow * 64 + vblk * 8];
        o[n] = __builtin_amdgcn_mfma_f32_16x16x32_bf16(pa[ks], vb, o[n], 0, 0, 0);
      }
    __builtin_amdgcn_s_setprio(0);
    __syncthreads();   // reads of cur done + stage of cur^1 landed
  }
#undef STAGE_KV

  // epilogue: normalize, scatter to attn buffer [t*B+b][D] bf16
#pragma unroll
  for (int r = 0; r < 4; r++) lsum[r] = 1.0f / lsum[r];
  const int tbase = qt * 64 + w * 16 + fg * 4;
#pragma unroll
  for (int n = 0; n < 4; n++) {
    const int dcol = n * 16 + fr;
#pragma unroll
    for (int r = 0; r < 4; r++) {
      const int tt = tbase + r;
      const float val = o[n][r] * lsum[r];
      Ob[((size_t)(tt * Bn + bb)) * Dn + hh * HDn + dcol] = bfbits(val);
    }
  }
}

// ---------------- launch ---------------------------------------------------
extern "C" void kernel_launch(void* const* d_in, const int* in_sizes, int n_in,
                              void* d_out, int out_size, void* d_ws,
                              size_t ws_size, hipStream_t stream) {
  (void)in_sizes; (void)n_in; (void)out_size; (void)ws_size;
  const float* x  = (const float*)d_in[0];
  const float* Wq = (const float*)d_in[1];
  const float* bq = (const float*)d_in[2];
  const float* Wk = (const float*)d_in[3];
  const float* bk = (const float*)d_in[4];
  const float* Wv = (const float*)d_in[5];
  const float* bv = (const float*)d_in[6];
  const float* Wo = (const float*)d_in[7];
  const float* bo = (const float*)d_in[8];
  float* out = (float*)d_out;

  // workspace carve-up (u16 elements), high-water 72 MB (proven size).
  // Aliases (stream-ordered, safe):
  //   vtb = xbf  (xbf dead after gemm_qkv; vtb written by transpose_v after)
  //   ab  = vb   (vb dead after transpose_v; ab written by attn_fwd after)
  unsigned short* ws  = (unsigned short*)d_ws;
  unsigned short* xbf = ws;                               // [8192][1024] 16MB
  unsigned short* wqb = xbf + (size_t)Mn * Kn;            // [1024][1024] 2MB
  unsigned short* wkb = wqb + (size_t)Dn * Dn;
  unsigned short* wvb = wkb + (size_t)Dn * Dn;
  unsigned short* wob = wvb + (size_t)Dn * Dn;
  unsigned short* qb  = wob + (size_t)Dn * Dn;            // [b][h][t][d] 16MB
  unsigned short* kb  = qb + (size_t)Mn * Dn;             // 16MB
  unsigned short* vb  = kb + (size_t)Mn * Dn;             // 16MB
  unsigned short* vtb = xbf;                              // [b][h][d][t] alias
  unsigned short* ab  = vb;                               // [t*B+b][D] alias

  cvt_all<<<2048, 256, 0, stream>>>(
      x, Wq, Wk, Wv, Wo, xbf, wqb, wkb, wvb, wob);

  gemm_qkv<<<dim3(Mn / 128, Dn / 128, 3), 256, 0, stream>>>(
      xbf, wqb, wkb, wvb, bq, bk, bv, qb, kb, vb);
  transpose_v<<<dim3(Tn / 64, Bn * Hn), 256, 0, stream>>>(vb, vtb);
  attn_fwd<<<dim3(Bn * Hn, Tn / 64), 256, 0, stream>>>(qb, kb, vtb, ab);
  gemm_out<<<dim3(Mn / 128, Dn / 128), 256, 0, stream>>>(ab, wob, bo, out);
}